// Round 1
// baseline (596.715 us; speedup 1.0000x reference)
//
#include <hip/hip_runtime.h>
#include <hip/hip_bf16.h>
#include <math.h>

using bf16 = __hip_bfloat16;
typedef __attribute__((ext_vector_type(8))) short short8;
typedef __attribute__((ext_vector_type(4))) short shortx4;
typedef __attribute__((ext_vector_type(4))) float floatx4;

// Problem constants
#define BB 16
#define NN 1024
#define DD 768
#define HH 12
#define HD 64
#define HID 3072

__device__ __forceinline__ floatx4 mfma_bf16(short8 a, short8 b, floatx4 c) {
  return __builtin_amdgcn_mfma_f32_16x16x32_bf16(a, b, c, 0, 0, 0);
}

__device__ __forceinline__ short bf16_bits(float f) {
  union { bf16 h; short s; } u;
  u.h = __float2bfloat16(f);
  return u.s;
}

__device__ __forceinline__ void async_copy16(const void* g, void* l) {
  __builtin_amdgcn_global_load_lds(
      (const __attribute__((address_space(1))) unsigned int*)g,
      (__attribute__((address_space(3))) unsigned int*)l,
      16, 0, 0);
}

// tanh-form gelu via exp2: gelu(x) = x * sigmoid(2*0.7978845608*(x+0.044715x^3))
// z = 2*log2(e)*0.7978845608*(x + 0.044715 x^3) = x*(A1 + A3*x^2)
__device__ __forceinline__ float gelu_f(float x) {
  const float z = x * fmaf(0.10294324f, x * x, 2.3022082f);
  const float e = exp2f(z);
  return x - x * __builtin_amdgcn_rcpf(e + 1.0f);
}

// ---------------------------------------------------------------------------
// fp32 -> bf16 conversion (weights), 4 elements/thread.
// ---------------------------------------------------------------------------
__global__ __launch_bounds__(256)
void cvt_kernel(const float* __restrict__ in, bf16* __restrict__ out, int n4)
{
  const int i = blockIdx.x * 256 + threadIdx.x;
  if (i >= n4) return;
  const float4 v = ((const float4*)in)[i];
  shortx4 o;
  o.x = bf16_bits(v.x); o.y = bf16_bits(v.y);
  o.z = bf16_bits(v.z); o.w = bf16_bits(v.w);
  ((shortx4*)out)[i] = o;
}

// ---------------------------------------------------------------------------
// LayerNorm: fp32 in, bf16 out. One block (256 thr) per row of 768.
// ---------------------------------------------------------------------------
__global__ __launch_bounds__(256)
void ln_kernel(const float* __restrict__ x, const float* __restrict__ g,
               const float* __restrict__ b, bf16* __restrict__ y)
{
  const int row = blockIdx.x;
  const int t = threadIdx.x;
  const float* xr = x + (size_t)row * DD;
  float v[3];
  float s = 0.f, s2 = 0.f;
#pragma unroll
  for (int i = 0; i < 3; ++i) {
    float f = xr[t + i * 256];
    v[i] = f;
    s += f;
    s2 += f * f;
  }
#pragma unroll
  for (int off = 1; off < 64; off <<= 1) {
    s  += __shfl_xor(s, off);
    s2 += __shfl_xor(s2, off);
  }
  __shared__ float red[2][4];
  const int wave = t >> 6, lane = t & 63;
  if (lane == 0) { red[0][wave] = s; red[1][wave] = s2; }
  __syncthreads();
  s  = red[0][0] + red[0][1] + red[0][2] + red[0][3];
  s2 = red[1][0] + red[1][1] + red[1][2] + red[1][3];
  const float mu = s * (1.f / DD);
  const float var = s2 * (1.f / DD) - mu * mu;
  const float inv = rsqrtf(var + 1e-6f);
  bf16* yr = y + (size_t)row * DD;
#pragma unroll
  for (int i = 0; i < 3; ++i) {
    int c = t + i * 256;
    yr[c] = __float2bfloat16((v[i] - mu) * inv * g[c] + b[c]);
  }
}

// ---------------------------------------------------------------------------
// GEMM v4: C[M,N] = A[M,K] @ W[N,K]^T, bf16 in, f32 accum.
// 256x256 tile, 8 waves (2M x 4N), K consumed in 32-deep slabs through a
// 4-slot LDS ring (4 x 32KB = 128KB). Per slab: 2 phases x 16 MFMA with
// {ds_read subtile | issue 2 global_load_lds | barrier | setprio MFMA | barrier}
// and ONE counted s_waitcnt vmcnt(8) per slab (prefetch distance = 2 slabs;
// never vmcnt(0) in the main loop). Staging is linear global_load_lds with
// pre-swizzled global source; reads XOR-swizzle the 16B k-chunk with the row
// (c' = quad ^ (r&3) ^ ((r>>2)&3)) -> uniform 8 lanes per bank-group.
// Hazards: WAR - slot (s+3)&3 == (s-1)&3 was last ds_read during slab s-1,
// retired (lgkm) before that slab's final barrier. RAW - slab s+1 is
// collectively confirmed by each wave's vmcnt(8) + the slab-s final barrier.
// Tail: prefetch index wraps mod NS (NS%4==0) so counts stay exact; vmcnt(0)
// drain after the loop (before endpgm / epilogue).
// EPI 0: C=bf16. EPI 1: C=fp32 +bias+res (float4). EPI 2: C=bf16 +bias+gelu.
// ---------------------------------------------------------------------------
template <int EPI>
__global__ __launch_bounds__(512, 2)
void gemm_kernel(const bf16* __restrict__ A, const bf16* __restrict__ W,
                 const float* __restrict__ bias, const float* __restrict__ res,
                 void* __restrict__ Cv, int N, int K)
{
  __shared__ __align__(16) short smem[65536];   // 128 KB: 4 slots x (A 8K + B 8K shorts)

  const int tid  = threadIdx.x;
  const int lane = tid & 63;
  const int w    = tid >> 6;         // wave 0..7
  const int wm   = w >> 2;           // 0..1 : M half (128 rows)
  const int wn   = w & 3;            // 0..3 : N quarter (64 cols)
  const int row16 = lane & 15, quad = lane >> 4;

  // panel-swizzled rasterization (PP row-tiles per panel) for L2 reuse of W
  const int gx = gridDim.x, gy = gridDim.y;
  const int lin = blockIdx.y * gx + blockIdx.x;
  const int PP  = (gy & 7) ? gy : 8;
  const int per = gx * PP;
  const int pan = lin / per, rem = lin % per;
  const int bm = (pan * PP + rem % PP) * 256;
  const int bn = (rem / PP) * 256;

  // ---- staging source (pre-swizzled global chunk) ----
  const int rloc = lane >> 2;                      // 0..15 row within 16-row chunk
  const int cl   = lane & 3;                       // LDS 16B chunk this lane fills
  const int swzs = (rloc & 3) ^ ((rloc >> 2) & 3);
  const int cg   = cl ^ swzs;                      // global chunk fetched
  const bf16* Ag = A + (size_t)(bm + w * 32 + rloc) * K + cg * 8;
  const bf16* Bg = W + (size_t)(bn + w * 32 + rloc) * K + cg * 8;
  const size_t a16 = (size_t)16 * K;
  const int stLds = w * 1024;                      // shorts: wave's 32-row region

  const int NS = K >> 5;                           // K/32 slabs; NS % 4 == 0

  // ---- fragment read lane offset (swizzled chunk) ----
  const int swzr = (row16 & 3) ^ ((row16 >> 2) & 3);
  const int cx   = (quad ^ swzr) * 8;              // shorts within a 64B row

#define SLOT(u) (((u) & 3) * 16384)
#define STAGE_A(u, ko) do { \
    async_copy16(Ag + (ko),        smem + SLOT(u) + stLds); \
    async_copy16(Ag + a16 + (ko),  smem + SLOT(u) + stLds + 512); } while (0)
#define STAGE_B(u, ko) do { \
    async_copy16(Bg + (ko),        smem + SLOT(u) + 8192 + stLds); \
    async_copy16(Bg + a16 + (ko),  smem + SLOT(u) + 8192 + stLds + 512); } while (0)

  // prologue: slabs 0..2 into slots 0..2
  for (int u = 0; u < 3; ++u) {
    const size_t ko = (size_t)u * 32;
    STAGE_A(u, ko);
    STAGE_B(u, ko);
  }

  floatx4 acc[8][4] = {};

  asm volatile("s_waitcnt vmcnt(8)" ::: "memory");   // slab 0 landed (1,2 in flight)
  __builtin_amdgcn_s_barrier();

  for (int s = 0; s < NS; ++s) {
    int u = s + 3; if (u >= NS) u -= NS;             // wrapped prefetch slab
    const size_t ko = (size_t)u * 32;
    const short* sAs = smem + SLOT(s);
    const short* sBs = sAs + 8192;

    // ---------------- phase A ----------------
    short8 af[4], bfr[4];
#pragma unroll
    for (int mt = 0; mt < 4; ++mt)
      af[mt] = *(const short8*)&sAs[(wm * 128 + mt * 16 + row16) * 32 + cx];
#pragma unroll
    for (int nt = 0; nt < 4; ++nt)
      bfr[nt] = *(const short8*)&sBs[(wn * 64 + nt * 16 + row16) * 32 + cx];
    STAGE_A(u, ko);
    __builtin_amdgcn_s_barrier();
    __builtin_amdgcn_s_setprio(1);
#pragma unroll
    for (int mt = 0; mt < 4; ++mt)
#pragma unroll
      for (int nt = 0; nt < 4; ++nt)
        acc[mt][nt] = mfma_bf16(bfr[nt], af[mt], acc[mt][nt]);   // C^T trick
    __builtin_amdgcn_s_setprio(0);
    __builtin_amdgcn_s_barrier();

    // ---------------- phase B ----------------
    short8 af2[4];
#pragma unroll
    for (int mt = 0; mt < 4; ++mt)
      af2[mt] = *(const short8*)&sAs[(wm * 128 + (mt + 4) * 16 + row16) * 32 + cx];
    STAGE_B(u, ko);
    __builtin_amdgcn_s_barrier();
    __builtin_amdgcn_s_setprio(1);
#pragma unroll
    for (int mt = 0; mt < 4; ++mt)
#pragma unroll
      for (int nt = 0; nt < 4; ++nt)
        acc[mt + 4][nt] = mfma_bf16(bfr[nt], af2[mt], acc[mt + 4][nt]);
    __builtin_amdgcn_s_setprio(0);
    asm volatile("s_waitcnt vmcnt(8)" ::: "memory"); // slab s+1 landed; s+2,s+3 in flight
    __builtin_amdgcn_s_barrier();
  }
  asm volatile("s_waitcnt vmcnt(0)" ::: "memory");   // drain wrapped prefetches
#undef SLOT
#undef STAGE_A
#undef STAGE_B

  // ---------------- epilogue ----------------
  floatx4 bias4[4] = {};
  if (EPI != 0) {
#pragma unroll
    for (int nt = 0; nt < 4; ++nt)
      bias4[nt] = *(const floatx4*)&bias[bn + wn * 64 + nt * 16 + quad * 4];
  }

#pragma unroll
  for (int mt = 0; mt < 8; ++mt) {
    const int row = bm + wm * 128 + mt * 16 + row16;
    if (EPI == 1) {
      const float* rr = res + (size_t)row * N;
      float* cr = (float*)Cv + (size_t)row * N;
#pragma unroll
      for (int nt = 0; nt < 4; ++nt) {
        const int col = bn + wn * 64 + nt * 16 + quad * 4;
        const floatx4 rv = *(const floatx4*)&rr[col];
        floatx4 o;
#pragma unroll
        for (int r = 0; r < 4; ++r) o[r] = acc[mt][nt][r] + bias4[nt][r] + rv[r];
        *(floatx4*)&cr[col] = o;
      }
    } else {
      bf16* cr = (bf16*)Cv + (size_t)row * N;
#pragma unroll
      for (int nt = 0; nt < 4; ++nt) {
        const int col = bn + wn * 64 + nt * 16 + quad * 4;
        shortx4 pk;
#pragma unroll
        for (int r = 0; r < 4; ++r) {
          float v = acc[mt][nt][r] + bias4[nt][r];
          if (EPI == 2) v = gelu_f(v);
          pk[r] = bf16_bits(v);
        }
        *(shortx4*)&cr[col] = pk;
      }
    }
  }
}

// ---------------------------------------------------------------------------
// V transpose: qkv [nb,N,3,H,64] -> Vt [nb*H, 64, N]
// ---------------------------------------------------------------------------
__global__ __launch_bounds__(256)
void vtrans_kernel(const bf16* __restrict__ qkv, bf16* __restrict__ vt)
{
  const int bh = blockIdx.y;
  const int b = bh / HH, h = bh % HH;
  const int n0 = blockIdx.x * 64;
  __shared__ __align__(16) short tile[64 * 72];
  const int tid = threadIdx.x;

  const int r = tid >> 2, c16 = (tid & 3) * 16;
  const bf16* src = qkv + (size_t)(b * NN + n0 + r) * 2304 + 2 * DD + h * 64 + c16;
  *(short8*)&tile[r * 72 + c16]     = *(const short8*)(src);
  *(short8*)&tile[r * 72 + c16 + 8] = *(const short8*)(src + 8);
  __syncthreads();

#pragma unroll
  for (int it = 0; it < 2; ++it) {
    const int d  = (tid >> 3) + it * 32;
    const int jg = (tid & 7) * 8;
    short8 o;
#pragma unroll
    for (int t = 0; t < 8; ++t) ((short*)&o)[t] = tile[(jg + t) * 72 + d];
    *(short8*)&vt[((size_t)bh * 64 + d) * NN + n0 + jg] = o;
  }
}

// ---------------------------------------------------------------------------
// Flash attention v3 (fixed-offset softmax, ones-MFMA row sums, S^T P-writes).
// Block = (b,h) x 128 Q rows; wave owns 32 rows.
// ---------------------------------------------------------------------------
__global__ __launch_bounds__(256, 2)
void attn_kernel(const bf16* __restrict__ qkv, const bf16* __restrict__ vt,
                 bf16* __restrict__ out)
{
  const int bh = blockIdx.y;
  const int b = bh / HH, h = bh % HH;
  const int q0 = blockIdx.x * 128;
  const int tid = threadIdx.x;
  const int lane = tid & 63;
  const int wave = tid >> 6;
  const int row16 = lane & 15, quad = lane >> 4;

  __shared__ __align__(16) short sK[64 * 72];     // [j][d]
  __shared__ __align__(16) short sVt[64 * 72];    // [d][j]
  __shared__ __align__(16) short sP[4][32 * 72];  // per-wave P [q][j]

  const bf16* base  = qkv + (size_t)b * NN * 2304 + h * 64;
  const bf16* vbase = vt + (size_t)bh * 64 * NN;

  short8 qf[2][2];
#pragma unroll
  for (int qg = 0; qg < 2; ++qg) {
    const bf16* qrow = base + (size_t)(q0 + wave * 32 + qg * 16 + row16) * 2304;
    qf[qg][0] = *(const short8*)(qrow + quad * 8);
    qf[qg][1] = *(const short8*)(qrow + 32 + quad * 8);
  }

  floatx4 o_acc[2][4] = {};
  floatx4 l_acc[2] = {};
  const short8 ones = { (short)0x3F80, (short)0x3F80, (short)0x3F80, (short)0x3F80,
                        (short)0x3F80, (short)0x3F80, (short)0x3F80, (short)0x3F80 };

  const int sr = tid >> 2;
  const int sc = (tid & 3) * 16;
  const float ESC = 0.1803368801f;   // log2(e)/8

  for (int jt = 0; jt < NN / 64; ++jt) {
    const int j0 = jt * 64;
    {
      const bf16* kp = base + (size_t)(j0 + sr) * 2304 + DD + sc;
      *(short8*)&sK[sr * 72 + sc]     = *(const short8*)(kp);
      *(short8*)&sK[sr * 72 + sc + 8] = *(const short8*)(kp + 8);
      const bf16* vp = vbase + (size_t)sr * NN + j0 + sc;
      *(short8*)&sVt[sr * 72 + sc]     = *(const short8*)(vp);
      *(short8*)&sVt[sr * 72 + sc + 8] = *(const short8*)(vp + 8);
    }
    __syncthreads();

#pragma unroll
    for (int nt = 0; nt < 4; ++nt) {
      short8 kb0 = *(const short8*)&sK[(nt * 16 + row16) * 72 + quad * 8];
      short8 kb1 = *(const short8*)&sK[(nt * 16 + row16) * 72 + 32 + quad * 8];
#pragma unroll
      for (int qg = 0; qg < 2; ++qg) {
        floatx4 st = {};
        st = mfma_bf16(kb0, qf[qg][0], st);
        st = mfma_bf16(kb1, qf[qg][1], st);
        shortx4 pk;
#pragma unroll
        for (int r = 0; r < 4; ++r)
          pk[r] = bf16_bits(exp2f(fminf(st[r] * ESC, 30.f)));
        *(shortx4*)&sP[wave][(qg * 16 + row16) * 72 + nt * 16 + quad * 4] = pk;
      }
    }

    short8 vb[4][2];
#pragma unroll
    for (int dt = 0; dt < 4; ++dt) {
      vb[dt][0] = *(const short8*)&sVt[(dt * 16 + row16) * 72 + quad * 8];
      vb[dt][1] = *(const short8*)&sVt[(dt * 16 + row16) * 72 + 32 + quad * 8];
    }
#pragma unroll
    for (int qg = 0; qg < 2; ++qg) {
      short8 pf0 = *(const short8*)&sP[wave][(qg * 16 + row16) * 72 + quad * 8];
      short8 pf1 = *(const short8*)&sP[wave][(qg * 16 + row16) * 72 + 32 + quad * 8];
      l_acc[qg] = mfma_bf16(pf0, ones, l_acc[qg]);
      l_acc[qg] = mfma_bf16(pf1, ones, l_acc[qg]);
#pragma unroll
      for (int dt = 0; dt < 4; ++dt) {
        o_acc[qg][dt] = mfma_bf16(pf0, vb[dt][0], o_acc[qg][dt]);
        o_acc[qg][dt] = mfma_bf16(pf1, vb[dt][1], o_acc[qg][dt]);
      }
    }
    __syncthreads();
  }

#pragma unroll
  for (int qg = 0; qg < 2; ++qg) {
#pragma unroll
    for (int r = 0; r < 4; ++r) {
      const float inv = 1.f / l_acc[qg][r];
      const size_t n = (size_t)(b * NN + q0 + wave * 32 + qg * 16 + quad * 4 + r);
#pragma unroll
      for (int dt = 0; dt < 4; ++dt) {
        out[n * DD + h * 64 + dt * 16 + row16] =
            __float2bfloat16(o_acc[qg][dt][r] * inv);
      }
    }
  }
}

// ---------------------------------------------------------------------------
extern "C" void kernel_launch(void* const* d_in, const int* in_sizes, int n_in,
                              void* d_out, int out_size, void* d_ws, size_t ws_size,
                              hipStream_t stream)
{
  const float* x       = (const float*)d_in[0];
  const float* qkv_w   = (const float*)d_in[1];
  const float* proj_w  = (const float*)d_in[2];
  const float* proj_b  = (const float*)d_in[3];
  const float* fc1_w   = (const float*)d_in[4];
  const float* fc1_b   = (const float*)d_in[5];
  const float* fc2_w   = (const float*)d_in[6];
  const float* fc2_b   = (const float*)d_in[7];
  const float* norm1_g = (const float*)d_in[8];
  const float* norm1_b = (const float*)d_in[9];
  const float* norm2_g = (const float*)d_in[10];
  const float* norm2_b = (const float*)d_in[11];
  float* out = (float*)d_out;

  const int M = BB * NN;  // 16384 rows
  char* ws = (char*)d_ws;

  bf16* wq = (bf16*)ws;                                  // [2304,768]
  bf16* wp = wq + (size_t)3 * DD * DD;                   // [768,768]
  bf16* w1 = wp + (size_t)DD * DD;                       // [3072,768]
  bf16* w2 = w1 + (size_t)HID * DD;                      // [768,3072]
  bf16* xn = w2 + (size_t)DD * HID;                      // [M,768] bf16
  char* p2 = (char*)(xn + (size_t)M * DD);
  const size_t base_b = (size_t)(p2 - ws);               // 39,321,600

  int NBc = 1;
  for (int c = 16; c >= 1; c >>= 1)
    if (ws_size >= base_b + (size_t)c * 1024 * 7680) { NBc = c; break; }

  const int Rc = NBc * NN;
  bf16* qkvb = (bf16*)p2;                        // [Rc, 2304]
  bf16* aob  = qkvb + (size_t)Rc * 2304;         // [Rc, 768]
  bf16* vtb  = aob  + (size_t)Rc * DD;           // [NBc*H, 64, N]
  bf16* hb   = (bf16*)p2;                        // [Rc, 3072] (MLP phase)

  cvt_kernel<<<(3 * DD * DD / 4 + 255) / 256, 256, 0, stream>>>(qkv_w, wq, 3 * DD * DD / 4);
  cvt_kernel<<<(DD * DD / 4 + 255) / 256, 256, 0, stream>>>(proj_w, wp, DD * DD / 4);
  cvt_kernel<<<(HID * DD / 4 + 255) / 256, 256, 0, stream>>>(fc1_w, w1, HID * DD / 4);
  cvt_kernel<<<(DD * HID / 4 + 255) / 256, 256, 0, stream>>>(fc2_w, w2, DD * HID / 4);

  ln_kernel<<<M, 256, 0, stream>>>(x, norm1_g, norm1_b, xn);

  for (int c = 0; c < BB / NBc; ++c) {
    const size_t r0 = (size_t)c * Rc;
    gemm_kernel<0><<<dim3(3 * DD / 256, Rc / 256), 512, 0, stream>>>(
        xn + r0 * DD, wq, nullptr, nullptr, qkvb, 3 * DD, DD);
    vtrans_kernel<<<dim3(NN / 64, NBc * HH), 256, 0, stream>>>(qkvb, vtb);
    attn_kernel<<<dim3(NN / 128, NBc * HH), 256, 0, stream>>>(qkvb, vtb, aob);
    gemm_kernel<1><<<dim3(DD / 256, Rc / 256), 512, 0, stream>>>(
        aob, wp, proj_b, x + r0 * DD, out + r0 * DD, DD, DD);
  }

  ln_kernel<<<M, 256, 0, stream>>>(out, norm2_g, norm2_b, xn);

  for (int c = 0; c < BB / NBc; ++c) {
    const size_t r0 = (size_t)c * Rc;
    gemm_kernel<2><<<dim3(HID / 256, Rc / 256), 512, 0, stream>>>(
        xn + r0 * DD, w1, fc1_b, nullptr, hb, HID, DD);
    gemm_kernel<1><<<dim3(DD / 256, Rc / 256), 512, 0, stream>>>(
        hb, w2, fc2_b, out + r0 * DD, out + r0 * DD, DD, HID);
  }
}